// Round 4
// baseline (906.690 us; speedup 1.0000x reference)
//
#include <hip/hip_runtime.h>

typedef __attribute__((ext_vector_type(4))) float   f32x4;
typedef __attribute__((ext_vector_type(8))) __bf16  bf16x8;
typedef __attribute__((ext_vector_type(4))) __bf16  bf16x4;
typedef __attribute__((ext_vector_type(8))) unsigned short u16x8;

#define NH   16
#define HD   128
#define TSEQ 2048
#define DM   2048
#define MT   4096   // B*T rows
#define NT   (DM / 64)  // K-tiles for 256^2 gemm

__device__ __forceinline__ f32x4 mfma_bf16(bf16x8 a, bf16x8 b, f32x4 c) {
  return __builtin_amdgcn_mfma_f32_16x16x32_bf16(a, b, c, 0, 0, 0);
}

// async global->LDS, 16B per lane. LDS dest must be wave-uniform base;
// HW writes base + lane*16 (guide §5 / m97).
__device__ __forceinline__ void gl_lds16(const __bf16* g, __bf16* l) {
  __builtin_amdgcn_global_load_lds(
      (const __attribute__((address_space(1))) void*)g,
      (__attribute__((address_space(3))) void*)l, 16, 0, 0);
}

// ---------------- f32 -> bf16 bulk converts (x + 4 weights, z=0..4) --------
__global__ __launch_bounds__(256) void k_cvtw(
    const float* __restrict__ X,
    const float* __restrict__ W0, const float* __restrict__ W1,
    const float* __restrict__ W2, const float* __restrict__ W3,
    __bf16* __restrict__ DX,
    __bf16* __restrict__ D0, __bf16* __restrict__ D1,
    __bf16* __restrict__ D2, __bf16* __restrict__ D3) {
  int z = blockIdx.z;
  const float* s = (z == 0) ? W0 : (z == 1) ? W1 : (z == 2) ? W2
                   : (z == 3) ? W3 : X;
  __bf16*      d = (z == 0) ? D0 : (z == 1) ? D1 : (z == 2) ? D2
                   : (z == 3) ? D3 : DX;
  int n4 = (z == 4) ? (MT * DM / 4) : (DM * DM / 4);
  int i = blockIdx.x * 256 + threadIdx.x;
  int stride = gridDim.x * 256;
  for (; i < n4; i += stride) {
    f32x4 v = ((const f32x4*)s)[i];
    bf16x4 o;
    o[0] = (__bf16)v[0]; o[1] = (__bf16)v[1];
    o[2] = (__bf16)v[2]; o[3] = (__bf16)v[3];
    ((bf16x4*)d)[i] = o;
  }
}

// ---------------- 256^2 double-buffered GEMM for QKV ----------------
// C = A(4096xK) @ B^T (B is NxK row-major). z selects (Wq,Wk,Wv)->(q,k,v).
// 8 waves (2M x 4N), BK=64, early-issue gl_lds staging, T2 swizzle
// (c ^ ((row&3)<<4) elements), T5 setprio, raw barriers, vmcnt(0)/tile.
// Output scattered bf16 to (B,H,T,HD).
__global__ __launch_bounds__(512, 2) void k_gemm256(
    const __bf16* __restrict__ A,
    const __bf16* __restrict__ B0, const __bf16* __restrict__ B1,
    const __bf16* __restrict__ B2,
    __bf16* __restrict__ D0, __bf16* __restrict__ D1,
    __bf16* __restrict__ D2) {
  // [buf][0=A,1=B][2 halves x 128 rows x 64 cols]
  __shared__ __bf16 lds[2][2][16384];

  const int z = blockIdx.z;
  const __bf16* __restrict__ Bm = (z == 0) ? B0 : (z == 1 ? B1 : B2);
  __bf16* Dst = (z == 0) ? D0 : (z == 1 ? D1 : D2);

  // XCD swizzle over 128 wgs (16 m-tiles x 8 n-tiles)
  const int bid = blockIdx.x;
  const int wg  = (bid & 7) * 16 + (bid >> 3);
  const int m0  = (wg >> 3) * 256;
  const int n0  = (wg & 7) * 256;

  const int tid  = threadIdx.x;
  const int lane = tid & 63, w = tid >> 6;   // 8 waves
  const int wr   = w >> 2, wc = w & 3;       // 2 M x 4 N
  const int g    = lane >> 4, li = lane & 15;

  const __bf16* __restrict__ Ap = A + (size_t)m0 * DM;
  const __bf16* __restrict__ Bp = Bm + (size_t)n0 * DM;

  // staging geometry: per issue, wave w writes LDS elems [w*512 .. +512)
  // of a half (128x64). row = q*64 + w*8 + (lane>>3), cols = scol..scol+7
  // where scol is the INVERSE-swizzled source column (rule 21).
  const int srow = w * 8 + (lane >> 3);
  const int scol = ((lane & 7) * 8) ^ (((lane >> 3) & 3) << 4);

#define STAGE256(WB, KT)                                                     \
  {                                                                          \
    const int k1_ = (KT) * 64;                                               \
    _Pragma("unroll") for (int ht = 0; ht < 4; ht++) {                       \
      const __bf16* sp_ = (ht < 2) ? Ap : Bp;                                \
      const int hf_ = ht & 1;                                                \
      _Pragma("unroll") for (int qq = 0; qq < 2; qq++) {                     \
        gl_lds16(&sp_[(size_t)(hf_ * 128 + qq * 64 + srow) * DM + k1_ + scol],\
                 &lds[WB][ht >> 1][hf_ * 8192 + qq * 4096 + w * 512]);       \
      }                                                                      \
    }                                                                        \
  }

  const f32x4 zero = {0.f, 0.f, 0.f, 0.f};
  f32x4 acc[8][4];
#pragma unroll
  for (int i = 0; i < 8; i++)
#pragma unroll
    for (int j = 0; j < 4; j++) acc[i][j] = zero;

// one quadrant phase: 12 swizzled ds_reads + 16 MFMA + barrier
#define QPHASE(RD, MQ, NQ)                                                   \
  {                                                                          \
    bf16x8 af_[4][2], bf_[2][2];                                             \
    _Pragma("unroll") for (int i = 0; i < 4; i++)                            \
      _Pragma("unroll") for (int kk = 0; kk < 2; kk++) {                     \
        const int rl_ = MQ * 64 + i * 16 + li;                               \
        af_[i][kk] = *(const bf16x8*)&lds[RD][0][                            \
            wr * 8192 + rl_ * 64 + ((kk * 32 + g * 8) ^ ((li & 3) << 4))];   \
      }                                                                      \
    _Pragma("unroll") for (int j = 0; j < 2; j++)                            \
      _Pragma("unroll") for (int kk = 0; kk < 2; kk++) {                     \
        const int rb_ = wc * 64 + NQ * 32 + j * 16 + li;                     \
        bf_[j][kk] = *(const bf16x8*)&lds[RD][1][                            \
            (rb_ >> 7) * 8192 + (rb_ & 127) * 64 +                           \
            ((kk * 32 + g * 8) ^ ((li & 3) << 4))];                          \
      }                                                                      \
    __builtin_amdgcn_s_setprio(1);                                           \
    _Pragma("unroll") for (int i = 0; i < 4; i++)                            \
      _Pragma("unroll") for (int j = 0; j < 2; j++)                          \
        _Pragma("unroll") for (int kk = 0; kk < 2; kk++)                     \
          acc[MQ * 4 + i][NQ * 2 + j] =                                      \
              mfma_bf16(af_[i][kk], bf_[j][kk], acc[MQ * 4 + i][NQ * 2 + j]);\
    __builtin_amdgcn_s_setprio(0);                                           \
    __builtin_amdgcn_s_barrier();                                            \
  }

  // prologue: stage tile 0 into buf 0
  STAGE256(0, 0);
  asm volatile("s_waitcnt vmcnt(0)" ::: "memory");
  __builtin_amdgcn_s_barrier();

  for (int t = 0; t < NT; ++t) {
    const int rd = t & 1;
    if (t + 1 < NT) {          // early issue: latency hides under 64 MFMA
      if (rd == 0) STAGE256(1, t + 1) else STAGE256(0, t + 1);
    }
    if (rd == 0) {
      QPHASE(0, 0, 0); QPHASE(0, 0, 1); QPHASE(0, 1, 0); QPHASE(0, 1, 1);
    } else {
      QPHASE(1, 0, 0); QPHASE(1, 0, 1); QPHASE(1, 1, 0); QPHASE(1, 1, 1);
    }
    asm volatile("s_waitcnt vmcnt(0)" ::: "memory");
    __builtin_amdgcn_s_barrier();
  }

  // epilogue: scatter bf16 to (B,H,T,HD)
#pragma unroll
  for (int i = 0; i < 8; i++) {
#pragma unroll
    for (int j = 0; j < 4; j++) {
      const int col = n0 + wc * 64 + j * 16 + li;
      const int h = col >> 7, d = col & 127;
#pragma unroll
      for (int r = 0; r < 4; r++) {
        const int row = m0 + wr * 128 + i * 16 + g * 4 + r;
        const int b = row >> 11, t = row & 2047;
        Dst[(((size_t)(b * NH + h)) * TSEQ + t) * HD + d] =
            (__bf16)acc[i][j][r];
      }
    }
  }
#undef STAGE256
#undef QPHASE
}

// ---------------- GEMM (m97 structure): out-proj, f32 output ----------------
__global__ __launch_bounds__(256) void k_gemm_o(const __bf16* __restrict__ A,
                                                const __bf16* __restrict__ Bm,
                                                float* __restrict__ F) {
  __shared__ __bf16 As[128 * 32];
  __shared__ __bf16 Bs[128 * 32];

  const int bid = blockIdx.x;
  const int wg  = (bid & 7) * 64 + (bid >> 3);
  const int n0  = (wg & 15) * 128;
  const int m0  = (wg >> 4) * 128;

  const int tid  = threadIdx.x;
  const int lane = tid & 63, w = tid >> 6;
  const int g    = lane >> 4, li = lane & 15;
  const int wr   = w >> 1, wc = w & 1;
  const int srow = lane >> 2;
  const int sseg = lane & 3;

  const f32x4 zero = {0.f, 0.f, 0.f, 0.f};
  f32x4 acc[4][4];
#pragma unroll
  for (int i = 0; i < 4; i++)
#pragma unroll
    for (int j = 0; j < 4; j++) acc[i][j] = zero;

  for (int k0 = 0; k0 < DM; k0 += 32) {
#pragma unroll
    for (int c = 0; c < 2; c++) {
      const int ch = w * 2 + c;
      gl_lds16(&A[(size_t)(m0 + ch * 16 + srow) * DM + k0 + sseg * 8],
               &As[ch * 512]);
      gl_lds16(&Bm[(size_t)(n0 + ch * 16 + srow) * DM + k0 + sseg * 8],
               &Bs[ch * 512]);
    }
    __syncthreads();
    bf16x8 af[4], bfr[4];
#pragma unroll
    for (int i = 0; i < 4; i++)
      af[i] = *(const bf16x8*)&As[(wr * 64 + i * 16 + li) * 32 + g * 8];
#pragma unroll
    for (int i = 0; i < 4; i++)
      bfr[i] = *(const bf16x8*)&Bs[(wc * 64 + i * 16 + li) * 32 + g * 8];
#pragma unroll
    for (int mi = 0; mi < 4; mi++)
#pragma unroll
      for (int ni = 0; ni < 4; ni++)
        acc[mi][ni] = mfma_bf16(af[mi], bfr[ni], acc[mi][ni]);
    __syncthreads();
  }

#pragma unroll
  for (int mi = 0; mi < 4; mi++)
#pragma unroll
    for (int ni = 0; ni < 4; ni++) {
      int colb = n0 + wc * 64 + ni * 16 + li;
#pragma unroll
      for (int r = 0; r < 4; r++) {
        int rowb = m0 + wr * 64 + mi * 16 + g * 4 + r;
        F[(size_t)rowb * DM + colb] = acc[mi][ni][r];
      }
    }
}

// ---------------- RoPE in-place on q and k (B,H,T,HD) ----------------
__global__ __launch_bounds__(256) void k_rope(__bf16* __restrict__ q,
                                              __bf16* __restrict__ kk,
                                              const float* __restrict__ rc,
                                              const float* __restrict__ rs) {
  int gid    = blockIdx.x * 256 + threadIdx.x;
  int tensor = gid >> 20;
  int rem    = gid & ((1 << 20) - 1);
  int bh     = rem >> 15;
  int r2     = rem & 32767;
  int t      = r2 >> 4;
  int j      = r2 & 15;
  int d0     = j * 4;
  __bf16* base = (tensor ? kk : q) + ((size_t)bh * TSEQ + t) * HD;
  f32x4 ca = *(const f32x4*)&rc[t * HD + d0];
  f32x4 cb = *(const f32x4*)&rc[t * HD + d0 + 64];
  f32x4 sa = *(const f32x4*)&rs[t * HD + d0];
  f32x4 sb = *(const f32x4*)&rs[t * HD + d0 + 64];
  bf16x4 xa = *(bf16x4*)&base[d0];
  bf16x4 xb = *(bf16x4*)&base[d0 + 64];
  bf16x4 oa, ob;
#pragma unroll
  for (int u = 0; u < 4; u++) {
    float fa = (float)xa[u], fb = (float)xb[u];
    oa[u] = (__bf16)(ca[u] * fa - fb * sa[u]);
    ob[u] = (__bf16)(cb[u] * fb + fa * sb[u]);
  }
  *(bf16x4*)&base[d0]      = oa;
  *(bf16x4*)&base[d0 + 64] = ob;
}

// ---------------- V (B,H,T,HD) -> Vt (B,H,HD,T) ----------------
__global__ __launch_bounds__(256) void k_trans(const __bf16* __restrict__ v,
                                               __bf16* __restrict__ vt) {
  __shared__ unsigned short tile[64][73];
  int bh = blockIdx.z;
  int t0 = blockIdx.x * 64, d0 = blockIdx.y * 64;
  int tid = threadIdx.x;
  int r = tid >> 2, s4 = tid & 3;
  const unsigned short* src =
      (const unsigned short*)v + ((size_t)bh * TSEQ + t0) * HD + d0;
  u16x8 a = *(const u16x8*)&src[(size_t)r * HD + s4 * 16];
  u16x8 b = *(const u16x8*)&src[(size_t)r * HD + s4 * 16 + 8];
#pragma unroll
  for (int u = 0; u < 8; u++) {
    tile[r][s4 * 16 + u]     = a[u];
    tile[r][s4 * 16 + 8 + u] = b[u];
  }
  __syncthreads();
  unsigned short* dst =
      (unsigned short*)vt + ((size_t)bh * HD + d0) * TSEQ + t0;
  u16x8 o1, o2;
#pragma unroll
  for (int u = 0; u < 8; u++) {
    o1[u] = tile[s4 * 16 + u][r];
    o2[u] = tile[s4 * 16 + 8 + u][r];
  }
  *(u16x8*)&dst[(size_t)r * TSEQ + s4 * 16]     = o1;
  *(u16x8*)&dst[(size_t)r * TSEQ + s4 * 16 + 8] = o2;
}

// ---------------- causal flash attention ----------------
// QBLK=128 (4 waves x 32 q-rows), KVBLK=64, T14 reg-staged K/V dbuf-free.
__global__ __launch_bounds__(256, 2) void k_attn(const __bf16* __restrict__ q,
                                                 const __bf16* __restrict__ k,
                                                 const __bf16* __restrict__ vt,
                                                 __bf16* __restrict__ ctx) {
  __shared__ __bf16 Ks[64 * 136];
  __shared__ __bf16 Vs[128 * 72];
  __shared__ __bf16 Ps[4][32 * 72];

  const int bid = blockIdx.x;
  const int wg  = (bid & 7) * 64 + (bid >> 3);
  const int bh  = wg >> 4;
  const int qt  = 15 - (wg & 15);
  const int q0  = qt * 128;

  const int tid  = threadIdx.x;
  const int lane = tid & 63, w = tid >> 6;
  const int g    = lane >> 4, li = lane & 15;
  const int qw   = q0 + w * 32;

  const __bf16* qb = q  + (size_t)bh * TSEQ * HD;
  const __bf16* kb = k  + (size_t)bh * TSEQ * HD;
  const __bf16* vb = vt + (size_t)bh * HD * TSEQ;

  const float CST = 0.08838834764831845f * 1.4426950408889634f;
  bf16x8 qf[2][4];
#pragma unroll
  for (int s = 0; s < 2; s++)
#pragma unroll
    for (int kc = 0; kc < 4; kc++) {
      bf16x8 t =
          *(const bf16x8*)&qb[(size_t)(qw + s * 16 + li) * HD + kc * 32 + g * 8];
      bf16x8 o;
#pragma unroll
      for (int e = 0; e < 8; e++) o[e] = (__bf16)((float)t[e] * CST);
      qf[s][kc] = o;
    }

  const f32x4 zero = {0.f, 0.f, 0.f, 0.f};
  f32x4 o[2][8];
#pragma unroll
  for (int s = 0; s < 2; s++)
#pragma unroll
    for (int dt = 0; dt < 8; dt++) o[s][dt] = zero;
  float mrow[2][4], lrow[2][4];
#pragma unroll
  for (int s = 0; s < 2; s++)
#pragma unroll
    for (int r = 0; r < 4; r++) { mrow[s][r] = -1e30f; lrow[s][r] = 0.f; }

  const int nkt = 2 * qt + 2;

  const int kR = tid >> 4, kS = tid & 15;
  const int vR = tid >> 3, vS = tid & 7;

  bf16x8 pk[4], pv[4];
#pragma unroll
  for (int i = 0; i < 4; i++) {
    pk[i] = *(const bf16x8*)&kb[(size_t)(kR + 16 * i) * HD + kS * 8];
    pv[i] = *(const bf16x8*)&vb[(size_t)(vR + 32 * i) * TSEQ + vS * 8];
  }

  for (int kt = 0; kt < nkt; kt++) {
    const int kv0 = kt * 64;
    __syncthreads();
#pragma unroll
    for (int i = 0; i < 4; i++)
      *(bf16x8*)&Ks[(kR + 16 * i) * 136 + kS * 8] = pk[i];
#pragma unroll
    for (int i = 0; i < 4; i++)
      *(bf16x8*)&Vs[(vR + 32 * i) * 72 + vS * 8] = pv[i];
    if (kt + 1 < nkt) {
      const int nv0 = kv0 + 64;
#pragma unroll
      for (int i = 0; i < 4; i++) {
        pk[i] = *(const bf16x8*)&kb[(size_t)(nv0 + kR + 16 * i) * HD + kS * 8];
        pv[i] = *(const bf16x8*)&vb[(size_t)(vR + 32 * i) * TSEQ + nv0 + vS * 8];
      }
    }
    __syncthreads();

    if (kv0 <= qw + 31) {
      f32x4 sc[2][4];
#pragma unroll
      for (int s = 0; s < 2; s++)
#pragma unroll
        for (int kvf = 0; kvf < 4; kvf++) sc[s][kvf] = zero;
#pragma unroll
      for (int kvf = 0; kvf < 4; kvf++)
#pragma unroll
        for (int kc = 0; kc < 4; kc++) {
          bf16x8 kf =
              *(const bf16x8*)&Ks[(kvf * 16 + li) * 136 + kc * 32 + g * 8];
          sc[0][kvf] = mfma_bf16(qf[0][kc], kf, sc[0][kvf]);
          sc[1][kvf] = mfma_bf16(qf[1][kc], kf, sc[1][kvf]);
        }
      if (kv0 + 63 > qw) {
#pragma unroll
        for (int s = 0; s < 2; s++)
#pragma unroll
          for (int kvf = 0; kvf < 4; kvf++) {
            int kg = kv0 + kvf * 16 + li;
#pragma unroll
            for (int r = 0; r < 4; r++) {
              int qg = qw + s * 16 + g * 4 + r;
              if (kg > qg) sc[s][kvf][r] = -1e30f;
            }
          }
      }
      float mnew[2][4];
      bool upd = false;
#pragma unroll
      for (int s = 0; s < 2; s++)
#pragma unroll
        for (int r = 0; r < 4; r++) {
          float a = fmaxf(fmaxf(sc[s][0][r], sc[s][1][r]),
                          fmaxf(sc[s][2][r], sc[s][3][r]));
          a = fmaxf(a, __shfl_xor(a, 1));
          a = fmaxf(a, __shfl_xor(a, 2));
          a = fmaxf(a, __shfl_xor(a, 4));
          a = fmaxf(a, __shfl_xor(a, 8));
          mnew[s][r] = fmaxf(mrow[s][r], a);
          upd = upd || (a > mrow[s][r]);
        }
      if (__any(upd)) {
#pragma unroll
        for (int s = 0; s < 2; s++)
#pragma unroll
          for (int r = 0; r < 4; r++) {
            float fac = __builtin_amdgcn_exp2f(mrow[s][r] - mnew[s][r]);
            mrow[s][r] = mnew[s][r];
            lrow[s][r] *= fac;
#pragma unroll
            for (int dt = 0; dt < 8; dt++) o[s][dt][r] *= fac;
          }
      }
#pragma unroll
      for (int s = 0; s < 2; s++)
#pragma unroll
        for (int kvf = 0; kvf < 4; kvf++) {
#pragma unroll
          for (int r = 0; r < 4; r++) {
            float p = __builtin_amdgcn_exp2f(sc[s][kvf][r] - mrow[s][r]);
            lrow[s][r] += p;
            Ps[w][(s * 16 + g * 4 + r) * 72 + kvf * 16 + li] = (__bf16)p;
          }
        }
      bf16x8 pa[2][2];
#pragma unroll
      for (int s = 0; s < 2; s++)
#pragma unroll
        for (int kvs = 0; kvs < 2; kvs++)
          pa[s][kvs] =
              *(const bf16x8*)&Ps[w][(s * 16 + li) * 72 + kvs * 32 + g * 8];
#pragma unroll
      for (int dt = 0; dt < 8; dt++) {
        bf16x8 v0 = *(const bf16x8*)&Vs[(dt * 16 + li) * 72 + g * 8];
        bf16x8 v1 = *(const bf16x8*)&Vs[(dt * 16 + li) * 72 + 32 + g * 8];
        o[0][dt] = mfma_bf16(pa[0][0], v0, o[0][dt]);
        o[0][dt] = mfma_bf16(pa[0][1], v1, o[0][dt]);
        o[1][dt] = mfma_bf16(pa[1][0], v0, o[1][dt]);
        o[1][dt] = mfma_bf16(pa[1][1], v1, o[1][dt]);
      }
    }
  }

  const int b = bh >> 4, h = bh & 15;
#pragma unroll
  for (int s = 0; s < 2; s++)
#pragma unroll
    for (int r = 0; r < 4; r++) {
      float l = lrow[s][r];
      l += __shfl_xor(l, 1);
      l += __shfl_xor(l, 2);
      l += __shfl_xor(l, 4);
      l += __shfl_xor(l, 8);
      float inv = 1.0f / l;
      size_t rowoff =
          ((size_t)(b * TSEQ + qw + s * 16 + g * 4 + r)) * DM + h * HD;
#pragma unroll
      for (int dt = 0; dt < 8; dt++)
        ctx[rowoff + dt * 16 + li] = (__bf16)(o[s][dt][r] * inv);
    }
}

// ---------------- launcher ----------------
extern "C" void kernel_launch(void* const* d_in, const int* in_sizes, int n_in,
                              void* d_out, int out_size, void* d_ws,
                              size_t ws_size, hipStream_t stream) {
  const float* x  = (const float*)d_in[0];
  const float* Wq = (const float*)d_in[1];
  const float* Wk = (const float*)d_in[2];
  const float* Wv = (const float*)d_in[3];
  const float* Wo = (const float*)d_in[4];
  const float* rc = (const float*)d_in[5];
  const float* rs = (const float*)d_in[6];
  float* out = (float*)d_out;

  __bf16* xb   = (__bf16*)d_ws;
  __bf16* wqb  = xb  + (size_t)MT * DM;
  __bf16* wkb  = wqb + (size_t)DM * DM;
  __bf16* wvb  = wkb + (size_t)DM * DM;
  __bf16* wob  = wvb + (size_t)DM * DM;
  __bf16* qbuf = wob + (size_t)DM * DM;
  __bf16* kbuf = qbuf + (size_t)MT * DM;
  __bf16* vbuf = kbuf + (size_t)MT * DM;
  __bf16* vtb  = vbuf + (size_t)MT * DM;
  __bf16* ctxb = vbuf;  // v dead after transpose; reuse for ctx

  dim3 gw(1024, 1, 5);
  k_cvtw<<<gw, 256, 0, stream>>>(x, Wq, Wk, Wv, Wo, xb, wqb, wkb, wvb, wob);

  dim3 gqkv(128, 1, 3);
  k_gemm256<<<gqkv, 512, 0, stream>>>(xb, wqb, wkb, wvb, qbuf, kbuf, vbuf);

  k_rope<<<8192, 256, 0, stream>>>(qbuf, kbuf, rc, rs);

  dim3 gt(TSEQ / 64, HD / 64, 32);
  k_trans<<<gt, 256, 0, stream>>>(vbuf, vtb);

  k_attn<<<512, 256, 0, stream>>>(qbuf, kbuf, vtb, ctxb);

  k_gemm_o<<<512, 256, 0, stream>>>(ctxb, wob, out);
}

// Round 5
// 456.914 us; speedup vs baseline: 1.9844x; 1.9844x over previous
//
#include <hip/hip_runtime.h>

typedef __attribute__((ext_vector_type(4))) float   f32x4;
typedef __attribute__((ext_vector_type(8))) __bf16  bf16x8;
typedef __attribute__((ext_vector_type(4))) __bf16  bf16x4;
typedef __attribute__((ext_vector_type(8))) unsigned short u16x8;

#define NH   16
#define HD   128
#define TSEQ 2048
#define DM   2048
#define MT   4096   // B*T rows

__device__ __forceinline__ f32x4 mfma_bf16(bf16x8 a, bf16x8 b, f32x4 c) {
  return __builtin_amdgcn_mfma_f32_16x16x32_bf16(a, b, c, 0, 0, 0);
}

// async global->LDS, 16B per lane. LDS dest must be wave-uniform base;
// HW writes base + lane*16 (guide §5 / m97).
__device__ __forceinline__ void gl_lds16(const __bf16* g, __bf16* l) {
  __builtin_amdgcn_global_load_lds(
      (const __attribute__((address_space(1))) void*)g,
      (__attribute__((address_space(3))) void*)l, 16, 0, 0);
}

// ---------------- f32 -> bf16 bulk converts (x + 4 weights, z=0..4) --------
__global__ __launch_bounds__(256) void k_cvtw(
    const float* __restrict__ X,
    const float* __restrict__ W0, const float* __restrict__ W1,
    const float* __restrict__ W2, const float* __restrict__ W3,
    __bf16* __restrict__ DX,
    __bf16* __restrict__ D0, __bf16* __restrict__ D1,
    __bf16* __restrict__ D2, __bf16* __restrict__ D3) {
  int z = blockIdx.z;
  const float* s = (z == 0) ? W0 : (z == 1) ? W1 : (z == 2) ? W2
                   : (z == 3) ? W3 : X;
  __bf16*      d = (z == 0) ? D0 : (z == 1) ? D1 : (z == 2) ? D2
                   : (z == 3) ? D3 : DX;
  int n4 = (z == 4) ? (MT * DM / 4) : (DM * DM / 4);
  int i = blockIdx.x * 256 + threadIdx.x;
  int stride = gridDim.x * 256;
  for (; i < n4; i += stride) {
    f32x4 v = ((const f32x4*)s)[i];
    bf16x4 o;
    o[0] = (__bf16)v[0]; o[1] = (__bf16)v[1];
    o[2] = (__bf16)v[2]; o[3] = (__bf16)v[3];
    ((bf16x4*)d)[i] = o;
  }
}

// ---------------- GEMM (m97 structure): C = A(MTxK) @ B^T ----------------
// 128x128 tile, BK=32, global_load_lds width-16 staging, linear LDS,
// XCD-chunked swizzle over 512 wgs. MODE 0: f32 row-major out.
// MODE 1: bf16 scatter to (B,H,T,HD).
template <int MODE>
__global__ __launch_bounds__(256) void k_gemm(const __bf16* __restrict__ A,
                                              const __bf16* __restrict__ Bm,
                                              __bf16* __restrict__ Dst,
                                              float* __restrict__ F) {
  __shared__ __bf16 As[128 * 32];
  __shared__ __bf16 Bs[128 * 32];

  const int bid = blockIdx.x;
  const int wg  = (bid & 7) * 64 + (bid >> 3);
  const int n0  = (wg & 15) * 128;
  const int m0  = (wg >> 4) * 128;

  const int tid  = threadIdx.x;
  const int lane = tid & 63, w = tid >> 6;
  const int g    = lane >> 4, li = lane & 15;
  const int wr   = w >> 1, wc = w & 1;
  const int srow = lane >> 2;   // staging: row within 16-row chunk
  const int sseg = lane & 3;    // staging: 16B segment within 64B row-part

  const f32x4 zero = {0.f, 0.f, 0.f, 0.f};
  f32x4 acc[4][4];
#pragma unroll
  for (int i = 0; i < 4; i++)
#pragma unroll
    for (int j = 0; j < 4; j++) acc[i][j] = zero;

  for (int k0 = 0; k0 < DM; k0 += 32) {
#pragma unroll
    for (int c = 0; c < 2; c++) {
      const int ch = w * 2 + c;  // 8 chunks of 16 rows each
      gl_lds16(&A[(size_t)(m0 + ch * 16 + srow) * DM + k0 + sseg * 8],
               &As[ch * 512]);
      gl_lds16(&Bm[(size_t)(n0 + ch * 16 + srow) * DM + k0 + sseg * 8],
               &Bs[ch * 512]);
    }
    __syncthreads();
    bf16x8 af[4], bfr[4];
#pragma unroll
    for (int i = 0; i < 4; i++)
      af[i] = *(const bf16x8*)&As[(wr * 64 + i * 16 + li) * 32 + g * 8];
#pragma unroll
    for (int i = 0; i < 4; i++)
      bfr[i] = *(const bf16x8*)&Bs[(wc * 64 + i * 16 + li) * 32 + g * 8];
#pragma unroll
    for (int mi = 0; mi < 4; mi++)
#pragma unroll
      for (int ni = 0; ni < 4; ni++)
        acc[mi][ni] = mfma_bf16(af[mi], bfr[ni], acc[mi][ni]);
    __syncthreads();
  }

#pragma unroll
  for (int mi = 0; mi < 4; mi++)
#pragma unroll
    for (int ni = 0; ni < 4; ni++) {
      int colb = n0 + wc * 64 + ni * 16 + li;
#pragma unroll
      for (int r = 0; r < 4; r++) {
        int rowb = m0 + wr * 64 + mi * 16 + g * 4 + r;
        float vv = acc[mi][ni][r];
        if (MODE == 0) {
          F[(size_t)rowb * DM + colb] = vv;
        } else {
          int h = colb >> 7, d = colb & 127;
          int b = rowb >> 11, t = rowb & 2047;
          Dst[(((size_t)(b * NH + h)) * TSEQ + t) * HD + d] = (__bf16)vv;
        }
      }
    }
}

// ---------------- RoPE in-place on q and k (B,H,T,HD) ----------------
__global__ __launch_bounds__(256) void k_rope(__bf16* __restrict__ q,
                                              __bf16* __restrict__ kk,
                                              const float* __restrict__ rc,
                                              const float* __restrict__ rs) {
  int gid    = blockIdx.x * 256 + threadIdx.x;
  int tensor = gid >> 20;
  int rem    = gid & ((1 << 20) - 1);
  int bh     = rem >> 15;
  int r2     = rem & 32767;
  int t      = r2 >> 4;
  int j      = r2 & 15;
  int d0     = j * 4;
  __bf16* base = (tensor ? kk : q) + ((size_t)bh * TSEQ + t) * HD;
  f32x4 ca = *(const f32x4*)&rc[t * HD + d0];
  f32x4 cb = *(const f32x4*)&rc[t * HD + d0 + 64];
  f32x4 sa = *(const f32x4*)&rs[t * HD + d0];
  f32x4 sb = *(const f32x4*)&rs[t * HD + d0 + 64];
  bf16x4 xa = *(bf16x4*)&base[d0];
  bf16x4 xb = *(bf16x4*)&base[d0 + 64];
  bf16x4 oa, ob;
#pragma unroll
  for (int u = 0; u < 4; u++) {
    float fa = (float)xa[u], fb = (float)xb[u];
    oa[u] = (__bf16)(ca[u] * fa - fb * sa[u]);
    ob[u] = (__bf16)(cb[u] * fb + fa * sb[u]);
  }
  *(bf16x4*)&base[d0]      = oa;
  *(bf16x4*)&base[d0 + 64] = ob;
}

// ---------------- V (B,H,T,HD) -> Vt (B,H,HD,T) ----------------
__global__ __launch_bounds__(256) void k_trans(const __bf16* __restrict__ v,
                                               __bf16* __restrict__ vt) {
  __shared__ unsigned short tile[64][73];
  int bh = blockIdx.z;
  int t0 = blockIdx.x * 64, d0 = blockIdx.y * 64;
  int tid = threadIdx.x;
  int r = tid >> 2, s4 = tid & 3;
  const unsigned short* src =
      (const unsigned short*)v + ((size_t)bh * TSEQ + t0) * HD + d0;
  u16x8 a = *(const u16x8*)&src[(size_t)r * HD + s4 * 16];
  u16x8 b = *(const u16x8*)&src[(size_t)r * HD + s4 * 16 + 8];
#pragma unroll
  for (int u = 0; u < 8; u++) {
    tile[r][s4 * 16 + u]     = a[u];
    tile[r][s4 * 16 + 8 + u] = b[u];
  }
  __syncthreads();
  unsigned short* dst =
      (unsigned short*)vt + ((size_t)bh * HD + d0) * TSEQ + t0;
  u16x8 o1, o2;
#pragma unroll
  for (int u = 0; u < 8; u++) {
    o1[u] = tile[s4 * 16 + u][r];
    o2[u] = tile[s4 * 16 + 8 + u][r];
  }
  *(u16x8*)&dst[(size_t)r * TSEQ + s4 * 16]     = o1;
  *(u16x8*)&dst[(size_t)r * TSEQ + s4 * 16 + 8] = o2;
}

// ---------------- causal flash attention ----------------
// QBLK=128 (4 waves x 32 q-rows), KVBLK=64, T14 reg-staged K/V.
__global__ __launch_bounds__(256, 2) void k_attn(const __bf16* __restrict__ q,
                                                 const __bf16* __restrict__ k,
                                                 const __bf16* __restrict__ vt,
                                                 __bf16* __restrict__ ctx) {
  __shared__ __bf16 Ks[64 * 136];
  __shared__ __bf16 Vs[128 * 72];
  __shared__ __bf16 Ps[4][32 * 72];

  const int bid = blockIdx.x;
  const int wg  = (bid & 7) * 64 + (bid >> 3);
  const int bh  = wg >> 4;
  const int qt  = 15 - (wg & 15);
  const int q0  = qt * 128;

  const int tid  = threadIdx.x;
  const int lane = tid & 63, w = tid >> 6;
  const int g    = lane >> 4, li = lane & 15;
  const int qw   = q0 + w * 32;

  const __bf16* qb = q  + (size_t)bh * TSEQ * HD;
  const __bf16* kb = k  + (size_t)bh * TSEQ * HD;
  const __bf16* vb = vt + (size_t)bh * HD * TSEQ;

  const float CST = 0.08838834764831845f * 1.4426950408889634f;
  bf16x8 qf[2][4];
#pragma unroll
  for (int s = 0; s < 2; s++)
#pragma unroll
    for (int kc = 0; kc < 4; kc++) {
      bf16x8 t =
          *(const bf16x8*)&qb[(size_t)(qw + s * 16 + li) * HD + kc * 32 + g * 8];
      bf16x8 o;
#pragma unroll
      for (int e = 0; e < 8; e++) o[e] = (__bf16)((float)t[e] * CST);
      qf[s][kc] = o;
    }

  const f32x4 zero = {0.f, 0.f, 0.f, 0.f};
  f32x4 o[2][8];
#pragma unroll
  for (int s = 0; s < 2; s++)
#pragma unroll
    for (int dt = 0; dt < 8; dt++) o[s][dt] = zero;
  float mrow[2][4], lrow[2][4];
#pragma unroll
  for (int s = 0; s < 2; s++)
#pragma unroll
    for (int r = 0; r < 4; r++) { mrow[s][r] = -1e30f; lrow[s][r] = 0.f; }

  const int nkt = 2 * qt + 2;

  const int kR = tid >> 4, kS = tid & 15;
  const int vR = tid >> 3, vS = tid & 7;

  bf16x8 pk[4], pv[4];
#pragma unroll
  for (int i = 0; i < 4; i++) {
    pk[i] = *(const bf16x8*)&kb[(size_t)(kR + 16 * i) * HD + kS * 8];
    pv[i] = *(const bf16x8*)&vb[(size_t)(vR + 32 * i) * TSEQ + vS * 8];
  }

  for (int kt = 0; kt < nkt; kt++) {
    const int kv0 = kt * 64;
    __syncthreads();
#pragma unroll
    for (int i = 0; i < 4; i++)
      *(bf16x8*)&Ks[(kR + 16 * i) * 136 + kS * 8] = pk[i];
#pragma unroll
    for (int i = 0; i < 4; i++)
      *(bf16x8*)&Vs[(vR + 32 * i) * 72 + vS * 8] = pv[i];
    if (kt + 1 < nkt) {
      const int nv0 = kv0 + 64;
#pragma unroll
      for (int i = 0; i < 4; i++) {
        pk[i] = *(const bf16x8*)&kb[(size_t)(nv0 + kR + 16 * i) * HD + kS * 8];
        pv[i] = *(const bf16x8*)&vb[(size_t)(vR + 32 * i) * TSEQ + nv0 + vS * 8];
      }
    }
    __syncthreads();

    if (kv0 <= qw + 31) {
      f32x4 sc[2][4];
#pragma unroll
      for (int s = 0; s < 2; s++)
#pragma unroll
        for (int kvf = 0; kvf < 4; kvf++) sc[s][kvf] = zero;
#pragma unroll
      for (int kvf = 0; kvf < 4; kvf++)
#pragma unroll
        for (int kc = 0; kc < 4; kc++) {
          bf16x8 kf =
              *(const bf16x8*)&Ks[(kvf * 16 + li) * 136 + kc * 32 + g * 8];
          sc[0][kvf] = mfma_bf16(qf[0][kc], kf, sc[0][kvf]);
          sc[1][kvf] = mfma_bf16(qf[1][kc], kf, sc[1][kvf]);
        }
      if (kv0 + 63 > qw) {
#pragma unroll
        for (int s = 0; s < 2; s++)
#pragma unroll
          for (int kvf = 0; kvf < 4; kvf++) {
            int kg = kv0 + kvf * 16 + li;
#pragma unroll
            for (int r = 0; r < 4; r++) {
              int qg = qw + s * 16 + g * 4 + r;
              if (kg > qg) sc[s][kvf][r] = -1e30f;
            }
          }
      }
      float mnew[2][4];
      bool upd = false;
#pragma unroll
      for (int s = 0; s < 2; s++)
#pragma unroll
        for (int r = 0; r < 4; r++) {
          float a = fmaxf(fmaxf(sc[s][0][r], sc[s][1][r]),
                          fmaxf(sc[s][2][r], sc[s][3][r]));
          a = fmaxf(a, __shfl_xor(a, 1));
          a = fmaxf(a, __shfl_xor(a, 2));
          a = fmaxf(a, __shfl_xor(a, 4));
          a = fmaxf(a, __shfl_xor(a, 8));
          mnew[s][r] = fmaxf(mrow[s][r], a);
          upd = upd || (a > mrow[s][r]);
        }
      if (__any(upd)) {
#pragma unroll
        for (int s = 0; s < 2; s++)
#pragma unroll
          for (int r = 0; r < 4; r++) {
            float fac = __builtin_amdgcn_exp2f(mrow[s][r] - mnew[s][r]);
            mrow[s][r] = mnew[s][r];
            lrow[s][r] *= fac;
#pragma unroll
            for (int dt = 0; dt < 8; dt++) o[s][dt][r] *= fac;
          }
      }
#pragma unroll
      for (int s = 0; s < 2; s++)
#pragma unroll
        for (int kvf = 0; kvf < 4; kvf++) {
#pragma unroll
          for (int r = 0; r < 4; r++) {
            float p = __builtin_amdgcn_exp2f(sc[s][kvf][r] - mrow[s][r]);
            lrow[s][r] += p;
            Ps[w][(s * 16 + g * 4 + r) * 72 + kvf * 16 + li] = (__bf16)p;
          }
        }
      bf16x8 pa[2][2];
#pragma unroll
      for (int s = 0; s < 2; s++)
#pragma unroll
        for (int kvs = 0; kvs < 2; kvs++)
          pa[s][kvs] =
              *(const bf16x8*)&Ps[w][(s * 16 + li) * 72 + kvs * 32 + g * 8];
#pragma unroll
      for (int dt = 0; dt < 8; dt++) {
        bf16x8 v0 = *(const bf16x8*)&Vs[(dt * 16 + li) * 72 + g * 8];
        bf16x8 v1 = *(const bf16x8*)&Vs[(dt * 16 + li) * 72 + 32 + g * 8];
        o[0][dt] = mfma_bf16(pa[0][0], v0, o[0][dt]);
        o[0][dt] = mfma_bf16(pa[0][1], v1, o[0][dt]);
        o[1][dt] = mfma_bf16(pa[1][0], v0, o[1][dt]);
        o[1][dt] = mfma_bf16(pa[1][1], v1, o[1][dt]);
      }
    }
  }

  const int b = bh >> 4, h = bh & 15;
#pragma unroll
  for (int s = 0; s < 2; s++)
#pragma unroll
    for (int r = 0; r < 4; r++) {
      float l = lrow[s][r];
      l += __shfl_xor(l, 1);
      l += __shfl_xor(l, 2);
      l += __shfl_xor(l, 4);
      l += __shfl_xor(l, 8);
      float inv = 1.0f / l;
      size_t rowoff =
          ((size_t)(b * TSEQ + qw + s * 16 + g * 4 + r)) * DM + h * HD;
#pragma unroll
      for (int dt = 0; dt < 8; dt++)
        ctx[rowoff + dt * 16 + li] = (__bf16)(o[s][dt][r] * inv);
    }
}

// ---------------- launcher ----------------
extern "C" void kernel_launch(void* const* d_in, const int* in_sizes, int n_in,
                              void* d_out, int out_size, void* d_ws,
                              size_t ws_size, hipStream_t stream) {
  const float* x  = (const float*)d_in[0];
  const float* Wq = (const float*)d_in[1];
  const float* Wk = (const float*)d_in[2];
  const float* Wv = (const float*)d_in[3];
  const float* Wo = (const float*)d_in[4];
  const float* rc = (const float*)d_in[5];
  const float* rs = (const float*)d_in[6];
  float* out = (float*)d_out;

  __bf16* xb   = (__bf16*)d_ws;
  __bf16* wqb  = xb  + (size_t)MT * DM;
  __bf16* wkb  = wqb + (size_t)DM * DM;
  __bf16* wvb  = wkb + (size_t)DM * DM;
  __bf16* wob  = wvb + (size_t)DM * DM;
  __bf16* qbuf = wob + (size_t)DM * DM;
  __bf16* kbuf = qbuf + (size_t)MT * DM;
  __bf16* vbuf = kbuf + (size_t)MT * DM;
  __bf16* vtb  = vbuf + (size_t)MT * DM;
  __bf16* ctxb = vbuf;  // v dead after transpose; reuse for ctx

  dim3 gw(1024, 1, 5);
  k_cvtw<<<gw, 256, 0, stream>>>(x, Wq, Wk, Wv, Wo, xb, wqb, wkb, wvb, wob);

  // QKV as three dispatches: same total work, surfaces k_attn in top-5
  k_gemm<1><<<512, 256, 0, stream>>>(xb, wqb, qbuf, nullptr);
  k_gemm<1><<<512, 256, 0, stream>>>(xb, wkb, kbuf, nullptr);
  k_gemm<1><<<512, 256, 0, stream>>>(xb, wvb, vbuf, nullptr);

  k_rope<<<8192, 256, 0, stream>>>(qbuf, kbuf, rc, rs);

  dim3 gt(TSEQ / 64, HD / 64, 32);
  k_trans<<<gt, 256, 0, stream>>>(vbuf, vtb);

  k_attn<<<512, 256, 0, stream>>>(qbuf, kbuf, vtb, ctxb);

  k_gemm<0><<<512, 256, 0, stream>>>(ctxb, wob, nullptr, out);
}

// Round 6
// 435.668 us; speedup vs baseline: 2.0811x; 1.0488x over previous
//
#include <hip/hip_runtime.h>

typedef __attribute__((ext_vector_type(4))) float   f32x4;
typedef __attribute__((ext_vector_type(8))) __bf16  bf16x8;
typedef __attribute__((ext_vector_type(4))) __bf16  bf16x4;
typedef __attribute__((ext_vector_type(8))) unsigned short u16x8;

#define NH   16
#define HD   128
#define TSEQ 2048
#define DM   2048
#define MT   4096   // B*T rows

__device__ __forceinline__ f32x4 mfma_bf16(bf16x8 a, bf16x8 b, f32x4 c) {
  return __builtin_amdgcn_mfma_f32_16x16x32_bf16(a, b, c, 0, 0, 0);
}

// async global->LDS, 16B per lane. LDS dest must be wave-uniform base;
// HW writes base + lane*16 (guide §5 / m97).
__device__ __forceinline__ void gl_lds16(const __bf16* g, __bf16* l) {
  __builtin_amdgcn_global_load_lds(
      (const __attribute__((address_space(1))) void*)g,
      (__attribute__((address_space(3))) void*)l, 16, 0, 0);
}

// ---------------- f32 -> bf16 bulk converts (x + 4 weights, z=0..4) --------
__global__ __launch_bounds__(256) void k_cvtw(
    const float* __restrict__ X,
    const float* __restrict__ W0, const float* __restrict__ W1,
    const float* __restrict__ W2, const float* __restrict__ W3,
    __bf16* __restrict__ DX,
    __bf16* __restrict__ D0, __bf16* __restrict__ D1,
    __bf16* __restrict__ D2, __bf16* __restrict__ D3) {
  int z = blockIdx.z;
  const float* s = (z == 0) ? W0 : (z == 1) ? W1 : (z == 2) ? W2
                   : (z == 3) ? W3 : X;
  __bf16*      d = (z == 0) ? D0 : (z == 1) ? D1 : (z == 2) ? D2
                   : (z == 3) ? D3 : DX;
  int n4 = (z == 4) ? (MT * DM / 4) : (DM * DM / 4);
  int i = blockIdx.x * 256 + threadIdx.x;
  int stride = gridDim.x * 256;
  for (; i < n4; i += stride) {
    f32x4 v = ((const f32x4*)s)[i];
    bf16x4 o;
    o[0] = (__bf16)v[0]; o[1] = (__bf16)v[1];
    o[2] = (__bf16)v[2]; o[3] = (__bf16)v[3];
    ((bf16x4*)d)[i] = o;
  }
}

// ---------------- GEMM (m97 structure): C = A(MTxK) @ B^T ----------------
// 128x128 tile, BK=32, global_load_lds width-16 staging, linear LDS,
// XCD-chunked swizzle over 512 wgs. MODE 0: f32 row-major out.
// MODE 1: bf16 scatter to (B,H,T,HD).
template <int MODE>
__global__ __launch_bounds__(256) void k_gemm(const __bf16* __restrict__ A,
                                              const __bf16* __restrict__ Bm,
                                              __bf16* __restrict__ Dst,
                                              float* __restrict__ F) {
  __shared__ __bf16 As[128 * 32];
  __shared__ __bf16 Bs[128 * 32];

  const int bid = blockIdx.x;
  const int wg  = (bid & 7) * 64 + (bid >> 3);
  const int n0  = (wg & 15) * 128;
  const int m0  = (wg >> 4) * 128;

  const int tid  = threadIdx.x;
  const int lane = tid & 63, w = tid >> 6;
  const int g    = lane >> 4, li = lane & 15;
  const int wr   = w >> 1, wc = w & 1;
  const int srow = lane >> 2;   // staging: row within 16-row chunk
  const int sseg = lane & 3;    // staging: 16B segment within 64B row-part

  const f32x4 zero = {0.f, 0.f, 0.f, 0.f};
  f32x4 acc[4][4];
#pragma unroll
  for (int i = 0; i < 4; i++)
#pragma unroll
    for (int j = 0; j < 4; j++) acc[i][j] = zero;

  for (int k0 = 0; k0 < DM; k0 += 32) {
#pragma unroll
    for (int c = 0; c < 2; c++) {
      const int ch = w * 2 + c;  // 8 chunks of 16 rows each
      gl_lds16(&A[(size_t)(m0 + ch * 16 + srow) * DM + k0 + sseg * 8],
               &As[ch * 512]);
      gl_lds16(&Bm[(size_t)(n0 + ch * 16 + srow) * DM + k0 + sseg * 8],
               &Bs[ch * 512]);
    }
    __syncthreads();
    bf16x8 af[4], bfr[4];
#pragma unroll
    for (int i = 0; i < 4; i++)
      af[i] = *(const bf16x8*)&As[(wr * 64 + i * 16 + li) * 32 + g * 8];
#pragma unroll
    for (int i = 0; i < 4; i++)
      bfr[i] = *(const bf16x8*)&Bs[(wc * 64 + i * 16 + li) * 32 + g * 8];
#pragma unroll
    for (int mi = 0; mi < 4; mi++)
#pragma unroll
      for (int ni = 0; ni < 4; ni++)
        acc[mi][ni] = mfma_bf16(af[mi], bfr[ni], acc[mi][ni]);
    __syncthreads();
  }

#pragma unroll
  for (int mi = 0; mi < 4; mi++)
#pragma unroll
    for (int ni = 0; ni < 4; ni++) {
      int colb = n0 + wc * 64 + ni * 16 + li;
#pragma unroll
      for (int r = 0; r < 4; r++) {
        int rowb = m0 + wr * 64 + mi * 16 + g * 4 + r;
        float vv = acc[mi][ni][r];
        if (MODE == 0) {
          F[(size_t)rowb * DM + colb] = vv;
        } else {
          int h = colb >> 7, d = colb & 127;
          int b = rowb >> 11, t = rowb & 2047;
          Dst[(((size_t)(b * NH + h)) * TSEQ + t) * HD + d] = (__bf16)vv;
        }
      }
    }
}

// ---------------- RoPE in-place on q and k (B,H,T,HD) ----------------
__global__ __launch_bounds__(256) void k_rope(__bf16* __restrict__ q,
                                              __bf16* __restrict__ kk,
                                              const float* __restrict__ rc,
                                              const float* __restrict__ rs) {
  int gid    = blockIdx.x * 256 + threadIdx.x;
  int tensor = gid >> 20;
  int rem    = gid & ((1 << 20) - 1);
  int bh     = rem >> 15;
  int r2     = rem & 32767;
  int t      = r2 >> 4;
  int j      = r2 & 15;
  int d0     = j * 4;
  __bf16* base = (tensor ? kk : q) + ((size_t)bh * TSEQ + t) * HD;
  f32x4 ca = *(const f32x4*)&rc[t * HD + d0];
  f32x4 cb = *(const f32x4*)&rc[t * HD + d0 + 64];
  f32x4 sa = *(const f32x4*)&rs[t * HD + d0];
  f32x4 sb = *(const f32x4*)&rs[t * HD + d0 + 64];
  bf16x4 xa = *(bf16x4*)&base[d0];
  bf16x4 xb = *(bf16x4*)&base[d0 + 64];
  bf16x4 oa, ob;
#pragma unroll
  for (int u = 0; u < 4; u++) {
    float fa = (float)xa[u], fb = (float)xb[u];
    oa[u] = (__bf16)(ca[u] * fa - fb * sa[u]);
    ob[u] = (__bf16)(cb[u] * fb + fa * sb[u]);
  }
  *(bf16x4*)&base[d0]      = oa;
  *(bf16x4*)&base[d0 + 64] = ob;
}

// ---------------- V (B,H,T,HD) -> Vt (B,H,HD,T) ----------------
__global__ __launch_bounds__(256) void k_trans(const __bf16* __restrict__ v,
                                               __bf16* __restrict__ vt) {
  __shared__ unsigned short tile[64][73];
  int bh = blockIdx.z;
  int t0 = blockIdx.x * 64, d0 = blockIdx.y * 64;
  int tid = threadIdx.x;
  int r = tid >> 2, s4 = tid & 3;
  const unsigned short* src =
      (const unsigned short*)v + ((size_t)bh * TSEQ + t0) * HD + d0;
  u16x8 a = *(const u16x8*)&src[(size_t)r * HD + s4 * 16];
  u16x8 b = *(const u16x8*)&src[(size_t)r * HD + s4 * 16 + 8];
#pragma unroll
  for (int u = 0; u < 8; u++) {
    tile[r][s4 * 16 + u]     = a[u];
    tile[r][s4 * 16 + 8 + u] = b[u];
  }
  __syncthreads();
  unsigned short* dst =
      (unsigned short*)vt + ((size_t)bh * HD + d0) * TSEQ + t0;
  u16x8 o1, o2;
#pragma unroll
  for (int u = 0; u < 8; u++) {
    o1[u] = tile[s4 * 16 + u][r];
    o2[u] = tile[s4 * 16 + 8 + u][r];
  }
  *(u16x8*)&dst[(size_t)r * TSEQ + s4 * 16]     = o1;
  *(u16x8*)&dst[(size_t)r * TSEQ + s4 * 16 + 8] = o2;
}

// ---------------- causal flash attention (swapped QK^T) ----------------
// QBLK=128 (4 waves x 32 q-rows), KVBLK=64, T14 reg-staged K/V.
// QK^T computed as mfma(K, Q) -> S^T: q = li (lane-local softmax stats),
// kv = kvf*16 + g*4 + r. P written as vectorized b64 into [q][kv] slab;
// PV reads unchanged. Max reduce: in-lane + 2 shfl. m/l lane-scalars.
__global__ __launch_bounds__(256, 2) void k_attn(const __bf16* __restrict__ q,
                                                 const __bf16* __restrict__ k,
                                                 const __bf16* __restrict__ vt,
                                                 __bf16* __restrict__ ctx) {
  __shared__ __bf16 Ks[64 * 136];
  __shared__ __bf16 Vs[128 * 72];
  __shared__ __bf16 Ps[4][32 * 72];

  const int bid = blockIdx.x;
  const int wg  = (bid & 7) * 64 + (bid >> 3);
  const int bh  = wg >> 4;
  const int qt  = 15 - (wg & 15);
  const int q0  = qt * 128;

  const int tid  = threadIdx.x;
  const int lane = tid & 63, w = tid >> 6;
  const int g    = lane >> 4, li = lane & 15;
  const int qw   = q0 + w * 32;

  const __bf16* qb = q  + (size_t)bh * TSEQ * HD;
  const __bf16* kb = k  + (size_t)bh * TSEQ * HD;
  const __bf16* vb = vt + (size_t)bh * HD * TSEQ;

  const float CST = 0.08838834764831845f * 1.4426950408889634f;
  bf16x8 qf[2][4];
#pragma unroll
  for (int s = 0; s < 2; s++)
#pragma unroll
    for (int kc = 0; kc < 4; kc++) {
      bf16x8 t =
          *(const bf16x8*)&qb[(size_t)(qw + s * 16 + li) * HD + kc * 32 + g * 8];
      bf16x8 o;
#pragma unroll
      for (int e = 0; e < 8; e++) o[e] = (__bf16)((float)t[e] * CST);
      qf[s][kc] = o;
    }

  const f32x4 zero = {0.f, 0.f, 0.f, 0.f};
  f32x4 o[2][8];
#pragma unroll
  for (int s = 0; s < 2; s++)
#pragma unroll
    for (int dt = 0; dt < 8; dt++) o[s][dt] = zero;
  float mrow[2] = {-1e30f, -1e30f};
  float lrow[2] = {0.f, 0.f};

  const int nkt = 2 * qt + 2;

  const int kR = tid >> 4, kS = tid & 15;
  const int vR = tid >> 3, vS = tid & 7;

  bf16x8 pk[4], pv[4];
#pragma unroll
  for (int i = 0; i < 4; i++) {
    pk[i] = *(const bf16x8*)&kb[(size_t)(kR + 16 * i) * HD + kS * 8];
    pv[i] = *(const bf16x8*)&vb[(size_t)(vR + 32 * i) * TSEQ + vS * 8];
  }

  for (int kt = 0; kt < nkt; kt++) {
    const int kv0 = kt * 64;
    __syncthreads();
#pragma unroll
    for (int i = 0; i < 4; i++)
      *(bf16x8*)&Ks[(kR + 16 * i) * 136 + kS * 8] = pk[i];
#pragma unroll
    for (int i = 0; i < 4; i++)
      *(bf16x8*)&Vs[(vR + 32 * i) * 72 + vS * 8] = pv[i];
    if (kt + 1 < nkt) {
      const int nv0 = kv0 + 64;
#pragma unroll
      for (int i = 0; i < 4; i++) {
        pk[i] = *(const bf16x8*)&kb[(size_t)(nv0 + kR + 16 * i) * HD + kS * 8];
        pv[i] = *(const bf16x8*)&vb[(size_t)(vR + 32 * i) * TSEQ + nv0 + vS * 8];
      }
    }
    __syncthreads();

    if (kv0 <= qw + 31) {
      // ---- swapped QK^T: sc[s][kvf] = S^T, rows kv, cols q=li ----
      f32x4 sc[2][4];
#pragma unroll
      for (int s = 0; s < 2; s++)
#pragma unroll
        for (int kvf = 0; kvf < 4; kvf++) sc[s][kvf] = zero;
#pragma unroll
      for (int kvf = 0; kvf < 4; kvf++)
#pragma unroll
        for (int kc = 0; kc < 4; kc++) {
          bf16x8 kf =
              *(const bf16x8*)&Ks[(kvf * 16 + li) * 136 + kc * 32 + g * 8];
          sc[0][kvf] = mfma_bf16(kf, qf[0][kc], sc[0][kvf]);
          sc[1][kvf] = mfma_bf16(kf, qf[1][kc], sc[1][kvf]);
        }
      // ---- causal mask: kv = kv0+kvf*16+g*4+r, q = qw+s*16+li ----
      if (kv0 + 63 > qw) {
#pragma unroll
        for (int s = 0; s < 2; s++) {
          const int qg = qw + s * 16 + li;
#pragma unroll
          for (int kvf = 0; kvf < 4; kvf++) {
#pragma unroll
            for (int r = 0; r < 4; r++) {
              int kg = kv0 + kvf * 16 + g * 4 + r;
              if (kg > qg) sc[s][kvf][r] = -1e30f;
            }
          }
        }
      }
      // ---- row max: in-lane over 16 kv, then reduce over g (2 shfl) ----
      float mnew[2];
      bool upd = false;
#pragma unroll
      for (int s = 0; s < 2; s++) {
        float a = fmaxf(fmaxf(sc[s][0][0], sc[s][0][1]),
                        fmaxf(sc[s][0][2], sc[s][0][3]));
#pragma unroll
        for (int kvf = 1; kvf < 4; kvf++) {
          float b0 = fmaxf(sc[s][kvf][0], sc[s][kvf][1]);
          float b1 = fmaxf(sc[s][kvf][2], sc[s][kvf][3]);
          a = fmaxf(a, fmaxf(b0, b1));
        }
        a = fmaxf(a, __shfl_xor(a, 16));
        a = fmaxf(a, __shfl_xor(a, 32));
        mnew[s] = fmaxf(mrow[s], a);
        upd = upd || (a > mrow[s]);
      }
      if (__any(upd)) {  // exact defer: skip rescale when no max grew
#pragma unroll
        for (int s = 0; s < 2; s++) {
          float fc = __builtin_amdgcn_exp2f(mrow[s] - mnew[s]);
          mrow[s] = mnew[s];
          lrow[s] *= fc;
#pragma unroll
          for (int r = 0; r < 4; r++) {
            float fr = __shfl(fc, (lane & 48) | (g * 4 + r));
#pragma unroll
            for (int dt = 0; dt < 8; dt++) o[s][dt][r] *= fr;
          }
        }
      }
      // ---- P = exp2(s - m) lane-local; vector b64 writes to [q][kv] ----
#pragma unroll
      for (int s = 0; s < 2; s++) {
#pragma unroll
        for (int kvf = 0; kvf < 4; kvf++) {
          bf16x4 pk4;
#pragma unroll
          for (int r = 0; r < 4; r++) {
            float p = __builtin_amdgcn_exp2f(sc[s][kvf][r] - mrow[s]);
            lrow[s] += p;
            pk4[r] = (__bf16)p;
          }
          *(bf16x4*)&Ps[w][(s * 16 + li) * 72 + kvf * 16 + g * 4] = pk4;
        }
      }
      // ---- PV: read P as A-frags, V as B-frags (unchanged layout) ----
      bf16x8 pa[2][2];
#pragma unroll
      for (int s = 0; s < 2; s++)
#pragma unroll
        for (int kvs = 0; kvs < 2; kvs++)
          pa[s][kvs] =
              *(const bf16x8*)&Ps[w][(s * 16 + li) * 72 + kvs * 32 + g * 8];
#pragma unroll
      for (int dt = 0; dt < 8; dt++) {
        bf16x8 v0 = *(const bf16x8*)&Vs[(dt * 16 + li) * 72 + g * 8];
        bf16x8 v1 = *(const bf16x8*)&Vs[(dt * 16 + li) * 72 + 32 + g * 8];
        o[0][dt] = mfma_bf16(pa[0][0], v0, o[0][dt]);
        o[0][dt] = mfma_bf16(pa[0][1], v1, o[0][dt]);
        o[1][dt] = mfma_bf16(pa[1][0], v0, o[1][dt]);
        o[1][dt] = mfma_bf16(pa[1][1], v1, o[1][dt]);
      }
    }
  }

  // ---- epilogue: reduce lane-scalar l over g, redistribute, write ----
  const int b = bh >> 4, h = bh & 15;
#pragma unroll
  for (int s = 0; s < 2; s++) {
    float l = lrow[s];
    l += __shfl_xor(l, 16);
    l += __shfl_xor(l, 32);
    float inv = 1.0f / l;
#pragma unroll
    for (int r = 0; r < 4; r++) {
      float ir = __shfl(inv, (lane & 48) | (g * 4 + r));
      size_t rowoff =
          ((size_t)(b * TSEQ + qw + s * 16 + g * 4 + r)) * DM + h * HD;
#pragma unroll
      for (int dt = 0; dt < 8; dt++)
        ctx[rowoff + dt * 16 + li] = (__bf16)(o[s][dt][r] * ir);
    }
  }
}

// ---------------- launcher ----------------
extern "C" void kernel_launch(void* const* d_in, const int* in_sizes, int n_in,
                              void* d_out, int out_size, void* d_ws,
                              size_t ws_size, hipStream_t stream) {
  const float* x  = (const float*)d_in[0];
  const float* Wq = (const float*)d_in[1];
  const float* Wk = (const float*)d_in[2];
  const float* Wv = (const float*)d_in[3];
  const float* Wo = (const float*)d_in[4];
  const float* rc = (const float*)d_in[5];
  const float* rs = (const float*)d_in[6];
  float* out = (float*)d_out;

  __bf16* xb   = (__bf16*)d_ws;
  __bf16* wqb  = xb  + (size_t)MT * DM;
  __bf16* wkb  = wqb + (size_t)DM * DM;
  __bf16* wvb  = wkb + (size_t)DM * DM;
  __bf16* wob  = wvb + (size_t)DM * DM;
  __bf16* qbuf = wob + (size_t)DM * DM;
  __bf16* kbuf = qbuf + (size_t)MT * DM;
  __bf16* vbuf = kbuf + (size_t)MT * DM;
  __bf16* vtb  = vbuf + (size_t)MT * DM;
  __bf16* ctxb = vbuf;  // v dead after transpose; reuse for ctx

  dim3 gw(1024, 1, 5);
  k_cvtw<<<gw, 256, 0, stream>>>(x, Wq, Wk, Wv, Wo, xb, wqb, wkb, wvb, wob);

  k_gemm<1><<<512, 256, 0, stream>>>(xb, wqb, qbuf, nullptr);
  k_gemm<1><<<512, 256, 0, stream>>>(xb, wkb, kbuf, nullptr);
  k_gemm<1><<<512, 256, 0, stream>>>(xb, wvb, vbuf, nullptr);

  k_rope<<<8192, 256, 0, stream>>>(qbuf, kbuf, rc, rs);

  dim3 gt(TSEQ / 64, HD / 64, 32);
  k_trans<<<gt, 256, 0, stream>>>(vbuf, vtb);

  k_attn<<<512, 256, 0, stream>>>(qbuf, kbuf, vtb, ctxb);

  k_gemm<0><<<512, 256, 0, stream>>>(ctxb, wob, nullptr, out);
}

// Round 9
// 414.322 us; speedup vs baseline: 2.1884x; 1.0515x over previous
//
#include <hip/hip_runtime.h>

typedef __attribute__((ext_vector_type(4))) float   f32x4;
typedef __attribute__((ext_vector_type(8))) __bf16  bf16x8;
typedef __attribute__((ext_vector_type(4))) __bf16  bf16x4;
typedef __attribute__((ext_vector_type(8))) unsigned short u16x8;

#define NH   16
#define HD   128
#define TSEQ 2048
#define DM   2048
#define MT   4096   // B*T rows

__device__ __forceinline__ f32x4 mfma_bf16(bf16x8 a, bf16x8 b, f32x4 c) {
  return __builtin_amdgcn_mfma_f32_16x16x32_bf16(a, b, c, 0, 0, 0);
}

// async global->LDS, 16B per lane. LDS dest must be wave-uniform base;
// HW writes base + lane*16 (guide §5 / m97).
__device__ __forceinline__ void gl_lds16(const __bf16* g, __bf16* l) {
  __builtin_amdgcn_global_load_lds(
      (const __attribute__((address_space(1))) void*)g,
      (__attribute__((address_space(3))) void*)l, 16, 0, 0);
}

// ---------------- f32 -> bf16 bulk converts (x + 4 weights, z=0..4) --------
__global__ __launch_bounds__(256) void k_cvtw(
    const float* __restrict__ X,
    const float* __restrict__ W0, const float* __restrict__ W1,
    const float* __restrict__ W2, const float* __restrict__ W3,
    __bf16* __restrict__ DX,
    __bf16* __restrict__ D0, __bf16* __restrict__ D1,
    __bf16* __restrict__ D2, __bf16* __restrict__ D3) {
  int z = blockIdx.z;
  const float* s = (z == 0) ? W0 : (z == 1) ? W1 : (z == 2) ? W2
                   : (z == 3) ? W3 : X;
  __bf16*      d = (z == 0) ? D0 : (z == 1) ? D1 : (z == 2) ? D2
                   : (z == 3) ? D3 : DX;
  int n4 = (z == 4) ? (MT * DM / 4) : (DM * DM / 4);
  int i = blockIdx.x * 256 + threadIdx.x;
  int stride = gridDim.x * 256;
  for (; i < n4; i += stride) {
    f32x4 v = ((const f32x4*)s)[i];
    bf16x4 o;
    o[0] = (__bf16)v[0]; o[1] = (__bf16)v[1];
    o[2] = (__bf16)v[2]; o[3] = (__bf16)v[3];
    ((bf16x4*)d)[i] = o;
  }
}

// ---------------- GEMM (m97 structure): C = A(MTxK) @ B^T ----------------
// MODE 0: f32 row-major out. MODE 1: bf16 scatter to (B,H,T,HD).
template <int MODE>
__global__ __launch_bounds__(256) void k_gemm(const __bf16* __restrict__ A,
                                              const __bf16* __restrict__ Bm,
                                              __bf16* __restrict__ Dst,
                                              float* __restrict__ F) {
  __shared__ __bf16 As[128 * 32];
  __shared__ __bf16 Bs[128 * 32];

  const int bid = blockIdx.x;
  const int wg  = (bid & 7) * 64 + (bid >> 3);
  const int n0  = (wg & 15) * 128;
  const int m0  = (wg >> 4) * 128;

  const int tid  = threadIdx.x;
  const int lane = tid & 63, w = tid >> 6;
  const int g    = lane >> 4, li = lane & 15;
  const int wr   = w >> 1, wc = w & 1;
  const int srow = lane >> 2;
  const int sseg = lane & 3;

  const f32x4 zero = {0.f, 0.f, 0.f, 0.f};
  f32x4 acc[4][4];
#pragma unroll
  for (int i = 0; i < 4; i++)
#pragma unroll
    for (int j = 0; j < 4; j++) acc[i][j] = zero;

  for (int k0 = 0; k0 < DM; k0 += 32) {
#pragma unroll
    for (int c = 0; c < 2; c++) {
      const int ch = w * 2 + c;
      gl_lds16(&A[(size_t)(m0 + ch * 16 + srow) * DM + k0 + sseg * 8],
               &As[ch * 512]);
      gl_lds16(&Bm[(size_t)(n0 + ch * 16 + srow) * DM + k0 + sseg * 8],
               &Bs[ch * 512]);
    }
    __syncthreads();
    bf16x8 af[4], bfr[4];
#pragma unroll
    for (int i = 0; i < 4; i++)
      af[i] = *(const bf16x8*)&As[(wr * 64 + i * 16 + li) * 32 + g * 8];
#pragma unroll
    for (int i = 0; i < 4; i++)
      bfr[i] = *(const bf16x8*)&Bs[(wc * 64 + i * 16 + li) * 32 + g * 8];
#pragma unroll
    for (int mi = 0; mi < 4; mi++)
#pragma unroll
      for (int ni = 0; ni < 4; ni++)
        acc[mi][ni] = mfma_bf16(af[mi], bfr[ni], acc[mi][ni]);
    __syncthreads();
  }

#pragma unroll
  for (int mi = 0; mi < 4; mi++)
#pragma unroll
    for (int ni = 0; ni < 4; ni++) {
      int colb = n0 + wc * 64 + ni * 16 + li;
#pragma unroll
      for (int r = 0; r < 4; r++) {
        int rowb = m0 + wr * 64 + mi * 16 + g * 4 + r;
        float vv = acc[mi][ni][r];
        if (MODE == 0) {
          F[(size_t)rowb * DM + colb] = vv;
        } else {
          int h = colb >> 7, d = colb & 127;
          int b = rowb >> 11, t = rowb & 2047;
          Dst[(((size_t)(b * NH + h)) * TSEQ + t) * HD + d] = (__bf16)vv;
        }
      }
    }
}

// ---------------- GEMM + fused RoPE epilogue (for Q and K) ----------------
// Wave cols remapped to col = ni*32 + wc*16 + li so acc[mi][ni] (d) and
// acc[mi][ni+2] (d+64) form the RoPE pair in-thread. B-frag rows permuted
// to match. Output bf16 scatter to (B,H,T,HD).
__global__ __launch_bounds__(256) void k_gemm_rope(
    const __bf16* __restrict__ A, const __bf16* __restrict__ Bm,
    __bf16* __restrict__ Dst,
    const float* __restrict__ rc, const float* __restrict__ rs) {
  __shared__ __bf16 As[128 * 32];
  __shared__ __bf16 Bs[128 * 32];

  const int bid = blockIdx.x;
  const int wg  = (bid & 7) * 64 + (bid >> 3);
  const int n0  = (wg & 15) * 128;
  const int m0  = (wg >> 4) * 128;

  const int tid  = threadIdx.x;
  const int lane = tid & 63, w = tid >> 6;
  const int g    = lane >> 4, li = lane & 15;
  const int wr   = w >> 1, wc = w & 1;
  const int srow = lane >> 2;
  const int sseg = lane & 3;

  const f32x4 zero = {0.f, 0.f, 0.f, 0.f};
  f32x4 acc[4][4];
#pragma unroll
  for (int i = 0; i < 4; i++)
#pragma unroll
    for (int j = 0; j < 4; j++) acc[i][j] = zero;

  for (int k0 = 0; k0 < DM; k0 += 32) {
#pragma unroll
    for (int c = 0; c < 2; c++) {
      const int ch = w * 2 + c;
      gl_lds16(&A[(size_t)(m0 + ch * 16 + srow) * DM + k0 + sseg * 8],
               &As[ch * 512]);
      gl_lds16(&Bm[(size_t)(n0 + ch * 16 + srow) * DM + k0 + sseg * 8],
               &Bs[ch * 512]);
    }
    __syncthreads();
    bf16x8 af[4], bfr[4];
#pragma unroll
    for (int i = 0; i < 4; i++)
      af[i] = *(const bf16x8*)&As[(wr * 64 + i * 16 + li) * 32 + g * 8];
#pragma unroll
    for (int i = 0; i < 4; i++)   // row = within-tile col = i*32 + wc*16 + li
      bfr[i] = *(const bf16x8*)&Bs[(i * 32 + wc * 16 + li) * 32 + g * 8];
#pragma unroll
    for (int mi = 0; mi < 4; mi++)
#pragma unroll
      for (int ni = 0; ni < 4; ni++)
        acc[mi][ni] = mfma_bf16(af[mi], bfr[ni], acc[mi][ni]);
    __syncthreads();
  }

  // epilogue: in-thread RoPE on (d, d+64) pairs, then scatter
  const int h = n0 >> 7;           // block covers exactly one head
  const int dl = wc * 16 + li;     // base d within head for ni=0
#pragma unroll
  for (int mi = 0; mi < 4; mi++) {
#pragma unroll
    for (int r = 0; r < 4; r++) {
      const int rowb = m0 + wr * 64 + mi * 16 + g * 4 + r;
      const int b = rowb >> 11, t = rowb & 2047;
      const float* rcb = rc + t * HD;
      const float* rsb = rs + t * HD;
      __bf16* outb = Dst + (((size_t)(b * NH + h)) * TSEQ + t) * HD;
#pragma unroll
      for (int ni = 0; ni < 2; ni++) {
        const int d = ni * 32 + dl;          // 0..63
        const float vlo = acc[mi][ni][r];
        const float vhi = acc[mi][ni + 2][r];
        const float clo = rcb[d],      slo = rsb[d];
        const float chi = rcb[d + 64], shi = rsb[d + 64];
        outb[d]      = (__bf16)(clo * vlo - slo * vhi);
        outb[d + 64] = (__bf16)(chi * vhi + shi * vlo);
      }
    }
  }
}

// ---------------- V (B,H,T,HD) -> Vt (B,H,HD,T) ----------------
__global__ __launch_bounds__(256) void k_trans(const __bf16* __restrict__ v,
                                               __bf16* __restrict__ vt) {
  __shared__ unsigned short tile[64][73];
  int bh = blockIdx.z;
  int t0 = blockIdx.x * 64, d0 = blockIdx.y * 64;
  int tid = threadIdx.x;
  int r = tid >> 2, s4 = tid & 3;
  const unsigned short* src =
      (const unsigned short*)v + ((size_t)bh * TSEQ + t0) * HD + d0;
  u16x8 a = *(const u16x8*)&src[(size_t)r * HD + s4 * 16];
  u16x8 b = *(const u16x8*)&src[(size_t)r * HD + s4 * 16 + 8];
#pragma unroll
  for (int u = 0; u < 8; u++) {
    tile[r][s4 * 16 + u]     = a[u];
    tile[r][s4 * 16 + 8 + u] = b[u];
  }
  __syncthreads();
  unsigned short* dst =
      (unsigned short*)vt + ((size_t)bh * HD + d0) * TSEQ + t0;
  u16x8 o1, o2;
#pragma unroll
  for (int u = 0; u < 8; u++) {
    o1[u] = tile[s4 * 16 + u][r];
    o2[u] = tile[s4 * 16 + 8 + u][r];
  }
  *(u16x8*)&dst[(size_t)r * TSEQ + s4 * 16]     = o1;
  *(u16x8*)&dst[(size_t)r * TSEQ + s4 * 16 + 8] = o2;
}

// ---------------- causal flash attention (swapped QK^T, paired tiles) ------
// Block = (bh, pair pi); processes q-tiles (15-pi) then (pi): 34 kv-tiles
// per block, exactly uniform. Grid 256 = 1 block/CU, zero tail.
__global__ __launch_bounds__(256, 2) void k_attn(const __bf16* __restrict__ q,
                                                 const __bf16* __restrict__ k,
                                                 const __bf16* __restrict__ vt,
                                                 __bf16* __restrict__ ctx) {
  __shared__ __bf16 Ks[64 * 136];
  __shared__ __bf16 Vs[128 * 72];
  __shared__ __bf16 Ps[4][32 * 72];

  const int bid = blockIdx.x;
  const int wg  = (bid & 7) * 32 + (bid >> 3);  // XCD chunking
  const int bh  = wg >> 3;
  const int pi  = wg & 7;

  const int tid  = threadIdx.x;
  const int lane = tid & 63, w = tid >> 6;
  const int g    = lane >> 4, li = lane & 15;

  const __bf16* qb = q  + (size_t)bh * TSEQ * HD;
  const __bf16* kb = k  + (size_t)bh * TSEQ * HD;
  const __bf16* vb = vt + (size_t)bh * HD * TSEQ;

  const float CST = 0.08838834764831845f * 1.4426950408889634f;
  const f32x4 zero = {0.f, 0.f, 0.f, 0.f};
  const int b = bh >> 4, h = bh & 15;

  const int kR = tid >> 4, kS = tid & 15;
  const int vR = tid >> 3, vS = tid & 7;

  for (int ph = 0; ph < 2; ph++) {
    const int qt = ph ? pi : (15 - pi);   // heavy first
    const int q0 = qt * 128;
    const int qw = q0 + w * 32;
    const int nkt = 2 * qt + 2;

    bf16x8 qf[2][4];
#pragma unroll
    for (int s = 0; s < 2; s++)
#pragma unroll
      for (int kc = 0; kc < 4; kc++) {
        bf16x8 t = *(const bf16x8*)&qb[(size_t)(qw + s * 16 + li) * HD +
                                       kc * 32 + g * 8];
        bf16x8 o;
#pragma unroll
        for (int e = 0; e < 8; e++) o[e] = (__bf16)((float)t[e] * CST);
        qf[s][kc] = o;
      }

    f32x4 o[2][8];
#pragma unroll
    for (int s = 0; s < 2; s++)
#pragma unroll
      for (int dt = 0; dt < 8; dt++) o[s][dt] = zero;
    float mrow[2] = {-1e30f, -1e30f};
    float lrow[2] = {0.f, 0.f};

    bf16x8 pk[4], pv[4];
#pragma unroll
    for (int i = 0; i < 4; i++) {
      pk[i] = *(const bf16x8*)&kb[(size_t)(kR + 16 * i) * HD + kS * 8];
      pv[i] = *(const bf16x8*)&vb[(size_t)(vR + 32 * i) * TSEQ + vS * 8];
    }

    for (int kt = 0; kt < nkt; kt++) {
      const int kv0 = kt * 64;
      __syncthreads();
#pragma unroll
      for (int i = 0; i < 4; i++)
        *(bf16x8*)&Ks[(kR + 16 * i) * 136 + kS * 8] = pk[i];
#pragma unroll
      for (int i = 0; i < 4; i++)
        *(bf16x8*)&Vs[(vR + 32 * i) * 72 + vS * 8] = pv[i];
      if (kt + 1 < nkt) {
        const int nv0 = kv0 + 64;
#pragma unroll
        for (int i = 0; i < 4; i++) {
          pk[i] = *(const bf16x8*)&kb[(size_t)(nv0 + kR + 16 * i) * HD + kS * 8];
          pv[i] =
              *(const bf16x8*)&vb[(size_t)(vR + 32 * i) * TSEQ + nv0 + vS * 8];
        }
      }
      __syncthreads();

      if (kv0 <= qw + 31) {
        // swapped QK^T: sc rows = kv, cols = q (li)
        f32x4 sc[2][4];
#pragma unroll
        for (int s = 0; s < 2; s++)
#pragma unroll
          for (int kvf = 0; kvf < 4; kvf++) sc[s][kvf] = zero;
#pragma unroll
        for (int kvf = 0; kvf < 4; kvf++)
#pragma unroll
          for (int kc = 0; kc < 4; kc++) {
            bf16x8 kf =
                *(const bf16x8*)&Ks[(kvf * 16 + li) * 136 + kc * 32 + g * 8];
            sc[0][kvf] = mfma_bf16(kf, qf[0][kc], sc[0][kvf]);
            sc[1][kvf] = mfma_bf16(kf, qf[1][kc], sc[1][kvf]);
          }
        if (kv0 + 63 > qw) {
#pragma unroll
          for (int s = 0; s < 2; s++) {
            const int qg = qw + s * 16 + li;
#pragma unroll
            for (int kvf = 0; kvf < 4; kvf++) {
#pragma unroll
              for (int r = 0; r < 4; r++) {
                int kg = kv0 + kvf * 16 + g * 4 + r;
                if (kg > qg) sc[s][kvf][r] = -1e30f;
              }
            }
          }
        }
        float mnew[2];
        bool upd = false;
#pragma unroll
        for (int s = 0; s < 2; s++) {
          float a = fmaxf(fmaxf(sc[s][0][0], sc[s][0][1]),
                          fmaxf(sc[s][0][2], sc[s][0][3]));
#pragma unroll
          for (int kvf = 1; kvf < 4; kvf++) {
            float b0 = fmaxf(sc[s][kvf][0], sc[s][kvf][1]);
            float b1 = fmaxf(sc[s][kvf][2], sc[s][kvf][3]);
            a = fmaxf(a, fmaxf(b0, b1));
          }
          a = fmaxf(a, __shfl_xor(a, 16));
          a = fmaxf(a, __shfl_xor(a, 32));
          mnew[s] = fmaxf(mrow[s], a);
          upd = upd || (a > mrow[s]);
        }
        if (__any(upd)) {
#pragma unroll
          for (int s = 0; s < 2; s++) {
            float fc = __builtin_amdgcn_exp2f(mrow[s] - mnew[s]);
            mrow[s] = mnew[s];
            lrow[s] *= fc;
#pragma unroll
            for (int r = 0; r < 4; r++) {
              float fr = __shfl(fc, (lane & 48) | (g * 4 + r));
#pragma unroll
              for (int dt = 0; dt < 8; dt++) o[s][dt][r] *= fr;
            }
          }
        }
#pragma unroll
        for (int s = 0; s < 2; s++) {
#pragma unroll
          for (int kvf = 0; kvf < 4; kvf++) {
            bf16x4 pk4;
#pragma unroll
            for (int r = 0; r < 4; r++) {
              float p = __builtin_amdgcn_exp2f(sc[s][kvf][r] - mrow[s]);
              lrow[s] += p;
              pk4[r] = (__bf16)p;
            }
            *(bf16x4*)&Ps[w][(s * 16 + li) * 72 + kvf * 16 + g * 4] = pk4;
          }
        }
        bf16x8 pa[2][2];
#pragma unroll
        for (int s = 0; s < 2; s++)
#pragma unroll
          for (int kvs = 0; kvs < 2; kvs++)
            pa[s][kvs] =
                *(const bf16x8*)&Ps[w][(s * 16 + li) * 72 + kvs * 32 + g * 8];
#pragma unroll
        for (int dt = 0; dt < 8; dt++) {
          bf16x8 v0 = *(const bf16x8*)&Vs[(dt * 16 + li) * 72 + g * 8];
          bf16x8 v1 = *(const bf16x8*)&Vs[(dt * 16 + li) * 72 + 32 + g * 8];
          o[0][dt] = mfma_bf16(pa[0][0], v0, o[0][dt]);
          o[0][dt] = mfma_bf16(pa[0][1], v1, o[0][dt]);
          o[1][dt] = mfma_bf16(pa[1][0], v0, o[1][dt]);
          o[1][dt] = mfma_bf16(pa[1][1], v1, o[1][dt]);
        }
      }
    }

    // phase epilogue
#pragma unroll
    for (int s = 0; s < 2; s++) {
      float l = lrow[s];
      l += __shfl_xor(l, 16);
      l += __shfl_xor(l, 32);
      float inv = 1.0f / l;
#pragma unroll
      for (int r = 0; r < 4; r++) {
        float ir = __shfl(inv, (lane & 48) | (g * 4 + r));
        size_t rowoff =
            ((size_t)(b * TSEQ + qw + s * 16 + g * 4 + r)) * DM + h * HD;
#pragma unroll
        for (int dt = 0; dt < 8; dt++)
          ctx[rowoff + dt * 16 + li] = (__bf16)(o[s][dt][r] * ir);
      }
    }
  }
}

// ---------------- launcher ----------------
extern "C" void kernel_launch(void* const* d_in, const int* in_sizes, int n_in,
                              void* d_out, int out_size, void* d_ws,
                              size_t ws_size, hipStream_t stream) {
  const float* x  = (const float*)d_in[0];
  const float* Wq = (const float*)d_in[1];
  const float* Wk = (const float*)d_in[2];
  const float* Wv = (const float*)d_in[3];
  const float* Wo = (const float*)d_in[4];
  const float* rc = (const float*)d_in[5];
  const float* rs = (const float*)d_in[6];
  float* out = (float*)d_out;

  __bf16* xb   = (__bf16*)d_ws;
  __bf16* wqb  = xb  + (size_t)MT * DM;
  __bf16* wkb  = wqb + (size_t)DM * DM;
  __bf16* wvb  = wkb + (size_t)DM * DM;
  __bf16* wob  = wvb + (size_t)DM * DM;
  __bf16* qbuf = wob + (size_t)DM * DM;
  __bf16* kbuf = qbuf + (size_t)MT * DM;
  __bf16* vbuf = kbuf + (size_t)MT * DM;
  __bf16* vtb  = vbuf + (size_t)MT * DM;
  __bf16* ctxb = vbuf;  // v dead after transpose; reuse for ctx

  dim3 gw(1024, 1, 5);
  k_cvtw<<<gw, 256, 0, stream>>>(x, Wq, Wk, Wv, Wo, xb, wqb, wkb, wvb, wob);

  k_gemm_rope<<<512, 256, 0, stream>>>(xb, wqb, qbuf, rc, rs);
  k_gemm_rope<<<512, 256, 0, stream>>>(xb, wkb, kbuf, rc, rs);
  k_gemm<1><<<512, 256, 0, stream>>>(xb, wvb, vbuf, nullptr);

  dim3 gt(TSEQ / 64, HD / 64, 32);
  k_trans<<<gt, 256, 0, stream>>>(vbuf, vtb);

  k_attn<<<256, 256, 0, stream>>>(qbuf, kbuf, vtb, ctxb);

  k_gemm<0><<<512, 256, 0, stream>>>(ctxb, wob, nullptr, out);
}